// Round 8
// baseline (551.989 us; speedup 1.0000x reference)
//
#include <hip/hip_runtime.h>
#include <cstdint>
#include <cstring>

#define B_ 32
#define N_ 128
#define F_ 128
#define SPLIT_ 8

typedef __attribute__((ext_vector_type(8))) __bf16 bf16x8;
typedef __attribute__((ext_vector_type(4))) float f32x4;

__device__ inline uint16_t f2bf_bits(float f) {
  __bf16 h = (__bf16)f;
  uint16_t u;
  __builtin_memcpy(&u, &h, 2);
  return u;
}

// ---------------- Kernel A: e_v = v_in @ W_ev + b_ev  -> ws ----------------
__global__ __launch_bounds__(128) void ev_kernel(const float* __restrict__ v_in,
                                                 const float* __restrict__ W_ev,
                                                 const float* __restrict__ b_ev,
                                                 float* __restrict__ e_v) {
  __shared__ float vr[8][F_];
  const int R0 = blockIdx.x * 8;
  const int tid = threadIdx.x;  // output feature g
#pragma unroll
  for (int i = 0; i < 8; ++i) vr[i][tid] = v_in[(size_t)(R0 + i) * F_ + tid];
  __syncthreads();
  float acc[8];
  const float bb = b_ev[tid];
#pragma unroll
  for (int i = 0; i < 8; ++i) acc[i] = bb;
  for (int f = 0; f < F_; ++f) {
    const float wv = W_ev[f * F_ + tid];
#pragma unroll
    for (int i = 0; i < 8; ++i) acc[i] += vr[i][f] * wv;
  }
#pragma unroll
  for (int i = 0; i < 8; ++i) e_v[(size_t)(R0 + i) * F_ + tid] = acc[i];
}

// ------- Kernel P: pack W_e (fp32 [128][128]) into bf16 MFMA fragments ------
// Tile t = kt*8+gt. Lane l holds 8 bf16: W_e[kt*32 + 8*(l>>4) + e][gt*16 + (l&15)].
__global__ void pack_kernel(const float* __restrict__ W_e, uint32_t* __restrict__ wp) {
  const int idx = blockIdx.x * 256 + threadIdx.x;  // 0..2047
  const int t = idx >> 6, l = idx & 63;
  const int kt = t >> 3, gt = t & 7;
  const int kbase = kt * 32 + ((l >> 4) << 3);
  const int g = gt * 16 + (l & 15);
#pragma unroll
  for (int p = 0; p < 4; ++p) {
    const uint32_t lo = f2bf_bits(W_e[(kbase + 2 * p) * F_ + g]);
    const uint32_t hi = f2bf_bits(W_e[(kbase + 2 * p + 1) * F_ + g]);
    wp[idx * 4 + p] = lo | (hi << 16);
  }
}

// ---------------- Kernel M: fused edge GEMM + epilogue ----------------------
// grid = 2048 (nt in high bits: adjacent blocks share (b,s), adjacent nt).
// 256 threads = 4 independent waves (no LDS/barriers). Wave w owns g-tiles
// {2w,2w+1}; 16-iter m-loop with DEPTH-2 register prefetch:
//   iter it: [wait+cvt tile it][issue loads tile it+2][MFMA it][stores it]
// "memory"-clobber asm fences prevent MachineSink from collapsing the
// rotation (R7 failure mode: loads sank to their use, VGPR_Count=64).
__global__ __launch_bounds__(256, 3) void main_kernel(
    const float* __restrict__ e_in, const float* __restrict__ e_v,
    const float* __restrict__ b_e, const bf16x8* __restrict__ wp,
    float* __restrict__ e_out, float* __restrict__ pve_part) {
  const int tid = threadIdx.x;
  const int w = tid >> 6, l = tid & 63;
  const int phys = blockIdx.x;
  const int nt = phys >> 8;        // 0..7
  const int grp = phys & 255;
  const int b = grp >> 3;          // 0..31
  const int s = grp & 7;           // 0..7
  const int n0 = nt * 16;
  const int lr = (l >> 4) << 2;    // g sub-base / D row group
  const int lc = l & 15;           // n within n-tile
  const int m0 = s * 16;

  // loop-invariant W fragments for this wave's 2 g-tiles (32 VGPRs)
  bf16x8 wreg[4][2];
#pragma unroll
  for (int kt = 0; kt < 4; ++kt)
#pragma unroll
    for (int j = 0; j < 2; ++j)
      wreg[kt][j] = wp[(kt * 8 + w * 2 + j) * 64 + l];

  // loop-invariant row term: e_v[b][n0+lc][g] + b_e[g]
  f32x4 evn[2];
#pragma unroll
  for (int j = 0; j < 2; ++j) {
    const int g0 = (w * 2 + j) * 16 + lr;
    evn[j] = *reinterpret_cast<const f32x4*>(&e_v[(size_t)(b * N_ + n0 + lc) * F_ + g0]) +
             *reinterpret_cast<const f32x4*>(&b_e[g0]);
  }

  f32x4 pve[2];
#pragma unroll
  for (int j = 0; j < 2; ++j) { pve[j][0] = 0.f; pve[j][1] = 0.f; pve[j][2] = 0.f; pve[j][3] = 0.f; }

  const float* lane_in =
      e_in + (((size_t)b * N_ + m0) * N_ + (n0 + lc)) * F_ + ((l >> 4) << 3);
  float* lane_out = e_out + (((size_t)b * N_ + m0) * N_ + (n0 + lc)) * F_;
  const float* evb = e_v + (size_t)b * N_ * F_;

  f32x4 f0[8], f1[8];  // depth-2 staging (64 VGPRs)
  f32x4 evr[2][2];     // evm ring

#define LOADS(dst, itn)                                                      \
  {                                                                          \
    const float* p_ = lane_in + (size_t)(itn) * (N_ * F_);                   \
    _Pragma("unroll") for (int kt_ = 0; kt_ < 4; ++kt_) {                    \
      dst[kt_ * 2] = *reinterpret_cast<const f32x4*>(p_ + kt_ * 32);         \
      dst[kt_ * 2 + 1] = *reinterpret_cast<const f32x4*>(p_ + kt_ * 32 + 4); \
    }                                                                        \
  }
#define EVML(dst, mm)                                                        \
  {                                                                          \
    _Pragma("unroll") for (int j_ = 0; j_ < 2; ++j_) {                       \
      const int g0_ = (w * 2 + j_) * 16 + lr;                                \
      dst[j_] = *reinterpret_cast<const f32x4*>(&evb[(size_t)(mm) * F_ + g0_]); \
    }                                                                        \
  }
#define CVT(aa, src)                                                         \
  {                                                                          \
    _Pragma("unroll") for (int kt_ = 0; kt_ < 4; ++kt_) {                    \
      _Pragma("unroll") for (int e_ = 0; e_ < 4; ++e_) {                     \
        aa[kt_][e_] = (__bf16)src[kt_ * 2][e_];                              \
        aa[kt_][e_ + 4] = (__bf16)src[kt_ * 2 + 1][e_];                      \
      }                                                                      \
    }                                                                        \
  }

  // prologue: tiles 0 and 1 in flight
  LOADS(f0, 0);
  EVML(evr[0], m0 + 0);
  asm volatile("" ::: "memory");
  LOADS(f1, 1);
  EVML(evr[1], m0 + 1);
  asm volatile("" ::: "memory");

  for (int it = 0; it < 16; ++it) {
    const int p = it & 1;
    // consume tile it: waits only loads issued at it-2 (newer stay in flight)
    f32x4 acc[2];
#pragma unroll
    for (int j = 0; j < 2; ++j) acc[j] = evn[j] + evr[p][j];
    bf16x8 a[4];
    if (p) { CVT(a, f1); } else { CVT(a, f0); }
    __builtin_amdgcn_sched_barrier(0);

    // issue tile it+2 (pinned here by the memory clobber below)
    if (it < 14) {
      if (p) { LOADS(f1, it + 2); } else { LOADS(f0, it + 2); }
      EVML(evr[p], m0 + it + 2);
    }
    asm volatile("" ::: "memory");
    __builtin_amdgcn_sched_barrier(0);

#pragma unroll
    for (int kt = 0; kt < 4; ++kt) {
      acc[0] = __builtin_amdgcn_mfma_f32_16x16x32_bf16(wreg[kt][0], a[kt], acc[0], 0, 0, 0);
      acc[1] = __builtin_amdgcn_mfma_f32_16x16x32_bf16(wreg[kt][1], a[kt], acc[1], 0, 0, 0);
    }

    float* op = lane_out + (size_t)it * (N_ * F_);
#pragma unroll
    for (int j = 0; j < 2; ++j) {
      const int g0 = (w * 2 + j) * 16 + lr;
      f32x4 v = acc[j];
#pragma unroll
      for (int q = 0; q < 4; ++q) v[q] = fmaxf(v[q], 0.f);
      pve[j] += v;
      *reinterpret_cast<f32x4*>(&op[g0]) = v;
    }
    asm volatile("" ::: "memory");
  }
#undef LOADS
#undef EVML
#undef CVT

  // wave owns its g-slice: write partial per_v_e directly
  float* pp = pve_part + (((size_t)s * B_ + b) * N_ + n0 + lc) * F_;
#pragma unroll
  for (int j = 0; j < 2; ++j)
    *reinterpret_cast<f32x4*>(&pp[(w * 2 + j) * 16 + lr]) = pve[j];
}

// ---------------- Kernel V: v_out = relu([sum(pve), v_in] @ W_v + b_v) ------
__global__ __launch_bounds__(128) void v_kernel(
    const float* __restrict__ v_in, const float* __restrict__ pve_part,
    const float* __restrict__ W_v, const float* __restrict__ b_v,
    float* __restrict__ v_out) {
  __shared__ float rows[8][256];
  const int R0 = blockIdx.x * 8;
  const int tid = threadIdx.x;
#pragma unroll
  for (int i = 0; i < 8; ++i) {
    const size_t r = R0 + i;
    float acc = 0.f;
#pragma unroll
    for (int s = 0; s < SPLIT_; ++s)
      acc += pve_part[((size_t)s * B_ * N_ + r) * F_ + tid];
    rows[i][tid] = acc;
    rows[i][128 + tid] = v_in[r * F_ + tid];
  }
  __syncthreads();
  float acc[8];
  const float bb = b_v[tid];
#pragma unroll
  for (int i = 0; i < 8; ++i) acc[i] = bb;
  for (int f = 0; f < 256; ++f) {
    const float wv = W_v[f * F_ + tid];
#pragma unroll
    for (int i = 0; i < 8; ++i) acc[i] += rows[i][f] * wv;
  }
#pragma unroll
  for (int i = 0; i < 8; ++i)
    v_out[(size_t)(R0 + i) * F_ + tid] = fmaxf(acc[i], 0.f);
}

extern "C" void kernel_launch(void* const* d_in, const int* in_sizes, int n_in,
                              void* d_out, int out_size, void* d_ws, size_t ws_size,
                              hipStream_t stream) {
  const float* v_in = (const float*)d_in[0];
  const float* e_in = (const float*)d_in[1];
  const float* W_ev = (const float*)d_in[2];
  const float* b_ev = (const float*)d_in[3];
  const float* W_e  = (const float*)d_in[4];
  const float* b_e  = (const float*)d_in[5];
  const float* W_v  = (const float*)d_in[6];
  const float* b_v  = (const float*)d_in[7];

  float* out = (float*)d_out;
  float* v_out = out;                         // [32,128,128]
  float* e_out = out + (size_t)B_ * N_ * F_;  // [32,128,128,128]

  char* ws = (char*)d_ws;
  float* e_v = (float*)ws;                                   // 2 MB
  uint32_t* wpack = (uint32_t*)(ws + (size_t)2097152);       // 64 KB slot
  float* pve_part = (float*)(ws + (size_t)2097152 + 65536);  // 16 MB

  ev_kernel<<<(B_ * N_) / 8, 128, 0, stream>>>(v_in, W_ev, b_ev, e_v);
  pack_kernel<<<8, 256, 0, stream>>>(W_e, wpack);
  main_kernel<<<B_ * 8 * SPLIT_, 256, 0, stream>>>(e_in, e_v, b_e,
                                                   (const bf16x8*)wpack,
                                                   e_out, pve_part);
  v_kernel<<<(B_ * N_) / 8, 128, 0, stream>>>(v_in, pve_part, W_v, b_v, v_out);
}

// Round 9
// 162.171 us; speedup vs baseline: 3.4037x; 3.4037x over previous
//
#include <hip/hip_runtime.h>
#include <cstdint>
#include <cstring>

#define B_ 32
#define N_ 128
#define F_ 128
#define SPLIT_ 4

typedef __attribute__((ext_vector_type(8))) __bf16 bf16x8;
typedef __attribute__((ext_vector_type(4))) float f32x4;

__device__ inline uint16_t f2bf_bits(float f) {
  __bf16 h = (__bf16)f;
  uint16_t u;
  __builtin_memcpy(&u, &h, 2);
  return u;
}

// async global->LDS, 16B per lane; dst is wave-uniform base (HW adds lane*16)
__device__ inline void gld16(const float* src, float* dst) {
  __builtin_amdgcn_global_load_lds(
      (const __attribute__((address_space(1))) unsigned int*)src,
      (__attribute__((address_space(3))) unsigned int*)dst, 16, 0, 0);
}

// ---------------- Kernel A: e_v = v_in @ W_ev + b_ev  -> ws ----------------
__global__ __launch_bounds__(128) void ev_kernel(const float* __restrict__ v_in,
                                                 const float* __restrict__ W_ev,
                                                 const float* __restrict__ b_ev,
                                                 float* __restrict__ e_v) {
  __shared__ float vr[8][F_];
  const int R0 = blockIdx.x * 8;
  const int tid = threadIdx.x;  // output feature g
#pragma unroll
  for (int i = 0; i < 8; ++i) vr[i][tid] = v_in[(size_t)(R0 + i) * F_ + tid];
  __syncthreads();
  float acc[8];
  const float bb = b_ev[tid];
#pragma unroll
  for (int i = 0; i < 8; ++i) acc[i] = bb;
  for (int f = 0; f < F_; ++f) {
    const float wv = W_ev[f * F_ + tid];
#pragma unroll
    for (int i = 0; i < 8; ++i) acc[i] += vr[i][f] * wv;
  }
#pragma unroll
  for (int i = 0; i < 8; ++i) e_v[(size_t)(R0 + i) * F_ + tid] = acc[i];
}

// ------- Kernel P: pack W_e (fp32 [128][128]) into bf16 MFMA fragments ------
// Tile t = kt*8+gt. Lane l holds 8 bf16: W_e[kt*32 + 8*(l>>4) + e][gt*16 + (l&15)].
__global__ void pack_kernel(const float* __restrict__ W_e, uint32_t* __restrict__ wp) {
  const int idx = blockIdx.x * 256 + threadIdx.x;  // 0..2047
  const int t = idx >> 6, l = idx & 63;
  const int kt = t >> 3, gt = t & 7;
  const int kbase = kt * 32 + ((l >> 4) << 3);
  const int g = gt * 16 + (l & 15);
#pragma unroll
  for (int p = 0; p < 4; ++p) {
    const uint32_t lo = f2bf_bits(W_e[(kbase + 2 * p) * F_ + g]);
    const uint32_t hi = f2bf_bits(W_e[(kbase + 2 * p + 1) * F_ + g]);
    wp[idx * 4 + p] = lo | (hi << 16);
  }
}

// ---------------- Kernel M: fused edge GEMM + epilogue ----------------------
// R3 structure + DEPTH-2 LDS pipeline.  grid = 32(b)*8(nt)*4(s), 512 thr =
// 8 waves; wave w: m-parity ml=w&1, g-quarter gq=w>>1 (2 g-tiles).
// Triple-buffered 16KB A-tiles (2 m-rows each); e_v m-rows pre-staged in LDS
// so loop VMEM = [gld16 x2][stores x2] per wave only.  Counted vmcnt:
// steady state vmcnt(6) = g(t+1) + st(t-1) + st(t-2) left in flight.
__global__ __launch_bounds__(512, 4) void main_kernel(
    const float* __restrict__ e_in, const float* __restrict__ e_v,
    const float* __restrict__ b_e, const bf16x8* __restrict__ wp,
    float* __restrict__ e_out, float* __restrict__ pve_part) {
  __shared__ __align__(16) float buf[3 * 4096];    // 48 KB: 3 x (2 m-rows)
  __shared__ __align__(16) float evlds[32 * F_];   // 16 KB: e_v[m0..m0+32)

  const int tid = threadIdx.x;
  const int w = tid >> 6, l = tid & 63;
  const int bid = blockIdx.x;
  const int s = bid & 3, nt = (bid >> 2) & 7, b = bid >> 5;
  const int n0 = nt * 16;
  const int lr = (l >> 4) << 2;  // g sub-base
  const int lc = l & 15;         // n within n-tile
  const int ml = w & 1;          // m parity
  const int gq = w >> 1;         // g quarter (2 g-tiles)
  const int m0 = s * 32;

  // loop-invariant W fragments (32 VGPRs)
  bf16x8 wreg[4][2];
#pragma unroll
  for (int kt = 0; kt < 4; ++kt)
#pragma unroll
    for (int j = 0; j < 2; ++j)
      wreg[kt][j] = wp[(kt * 8 + gq * 2 + j) * 64 + l];

  // loop-invariant row term: e_v[b][n0+lc][g] + b_e[g]  (global, prologue)
  f32x4 evn[2];
#pragma unroll
  for (int j = 0; j < 2; ++j) {
    const int g0 = (gq * 2 + j) * 16 + lr;
    evn[j] = *reinterpret_cast<const f32x4*>(&e_v[(size_t)(b * N_ + n0 + lc) * F_ + g0]) +
             *reinterpret_cast<const f32x4*>(&b_e[g0]);
  }

  f32x4 pve[2];
#pragma unroll
  for (int j = 0; j < 2; ++j) { pve[j][0] = 0.f; pve[j][1] = 0.f; pve[j][2] = 0.f; pve[j][3] = 0.f; }

  const float* einb = e_in + (size_t)b * N_ * N_ * F_;
  const float* evb = e_v + (size_t)b * N_ * F_;

  // stage e_v[b][m0..m0+32) into LDS (16 gld16 total, 2 per wave, linear)
#pragma unroll
  for (int q = 0; q < 2; ++q) {
    const int row0 = w * 4 + q * 2;
    gld16(evb + (size_t)(m0 + row0 + (l >> 5)) * F_ + (l & 31) * 4,
          &evlds[row0 * F_]);
  }

  // A staging: 2 gld16/wave/tile; instr t_=w*2+q: m-row mj=t_>>3, k=t_&7;
  // lane: row r = k*2+(l>>5), chunk c = (l&31)^(r&7)  (XOR source swizzle)
#define STAGE(q3, itn)                                                   \
  {                                                                      \
    _Pragma("unroll") for (int q_ = 0; q_ < 2; ++q_) {                   \
      const int t_ = w * 2 + q_;                                         \
      const int mj_ = t_ >> 3, k_ = t_ & 7;                              \
      const int m_ = m0 + (itn) * 2 + mj_;                               \
      const int r_ = k_ * 2 + (l >> 5);                                  \
      const int c_ = (l & 31) ^ (r_ & 7);                                \
      gld16(einb + ((size_t)m_ * N_ + n0 + r_) * F_ + c_ * 4,            \
            &buf[(q3) * 4096 + mj_ * 2048 + k_ * 256]);                  \
    }                                                                    \
  }

  STAGE(0, 0);
  STAGE(1, 1);

  const int swz = lc & 7;
  for (int it = 0; it < 16; ++it) {
    const int q3 = it % 3;
    // counted wait: tile it ready; newer prefetch + old stores stay in flight
    if (it == 0) {
      asm volatile("s_waitcnt vmcnt(2)" ::: "memory");
    } else if (it == 1 || it == 15) {
      asm volatile("s_waitcnt vmcnt(4)" ::: "memory");
    } else {
      asm volatile("s_waitcnt vmcnt(6)" ::: "memory");
    }
    __builtin_amdgcn_sched_barrier(0);
    __builtin_amdgcn_s_barrier();
    __builtin_amdgcn_sched_barrier(0);

    if (it < 14) STAGE((it + 2) % 3, it + 2);

    const int fb = q3 * 4096 + ml * 2048;
    f32x4 acc[2];
#pragma unroll
    for (int j = 0; j < 2; ++j) { acc[j][0] = 0.f; acc[j][1] = 0.f; acc[j][2] = 0.f; acc[j][3] = 0.f; }

#pragma unroll
    for (int kt = 0; kt < 4; ++kt) {
      const int cA = kt * 8 + ((l >> 4) << 1);
      const f32x4 f0 = *reinterpret_cast<const f32x4*>(
          &buf[fb + lc * 128 + ((cA ^ swz) << 2)]);
      const f32x4 f1 = *reinterpret_cast<const f32x4*>(
          &buf[fb + lc * 128 + (((cA + 1) ^ swz) << 2)]);
      bf16x8 a;
#pragma unroll
      for (int e = 0; e < 4; ++e) {
        a[e] = (__bf16)f0[e];
        a[e + 4] = (__bf16)f1[e];
      }
      acc[0] = __builtin_amdgcn_mfma_f32_16x16x32_bf16(wreg[kt][0], a, acc[0], 0, 0, 0);
      acc[1] = __builtin_amdgcn_mfma_f32_16x16x32_bf16(wreg[kt][1], a, acc[1], 0, 0, 0);
    }

    // epilogue: evm from LDS (uniform per 16-lane group -> broadcast, free)
    const int m = m0 + it * 2 + ml;
    const float* evmrow = &evlds[(it * 2 + ml) * F_];
    float* op = e_out + (((size_t)(b * N_) + m) * N_ + n0 + lc) * F_;
#pragma unroll
    for (int j = 0; j < 2; ++j) {
      const int g0 = (gq * 2 + j) * 16 + lr;
      f32x4 v = acc[j] + evn[j] + *reinterpret_cast<const f32x4*>(&evmrow[g0]);
#pragma unroll
      for (int q = 0; q < 4; ++q) v[q] = fmaxf(v[q], 0.f);
      pve[j] += v;
      *reinterpret_cast<f32x4*>(&op[g0]) = v;
    }
  }
#undef STAGE

  // cross-parity pve reduce: even wave writes, odd wave adds + stores
  __syncthreads();
  const int sbase = gq * 512 + lc * 32;
  if (ml == 0) {
#pragma unroll
    for (int j = 0; j < 2; ++j)
      *reinterpret_cast<f32x4*>(&buf[sbase + j * 16 + lr]) = pve[j];
  }
  __syncthreads();
  if (ml == 1) {
    float* pp = pve_part + (((size_t)s * B_ + b) * N_ + n0 + lc) * F_;
#pragma unroll
    for (int j = 0; j < 2; ++j) {
      const f32x4 sum = pve[j] + *reinterpret_cast<const f32x4*>(&buf[sbase + j * 16 + lr]);
      *reinterpret_cast<f32x4*>(&pp[(gq * 2 + j) * 16 + lr]) = sum;
    }
  }
}

// ---------------- Kernel V: v_out = relu([sum(pve), v_in] @ W_v + b_v) ------
__global__ __launch_bounds__(128) void v_kernel(
    const float* __restrict__ v_in, const float* __restrict__ pve_part,
    const float* __restrict__ W_v, const float* __restrict__ b_v,
    float* __restrict__ v_out) {
  __shared__ float rows[8][256];
  const int R0 = blockIdx.x * 8;
  const int tid = threadIdx.x;
#pragma unroll
  for (int i = 0; i < 8; ++i) {
    const size_t r = R0 + i;
    float acc = 0.f;
#pragma unroll
    for (int s = 0; s < SPLIT_; ++s)
      acc += pve_part[((size_t)s * B_ * N_ + r) * F_ + tid];
    rows[i][tid] = acc;
    rows[i][128 + tid] = v_in[r * F_ + tid];
  }
  __syncthreads();
  float acc[8];
  const float bb = b_v[tid];
#pragma unroll
  for (int i = 0; i < 8; ++i) acc[i] = bb;
  for (int f = 0; f < 256; ++f) {
    const float wv = W_v[f * F_ + tid];
#pragma unroll
    for (int i = 0; i < 8; ++i) acc[i] += rows[i][f] * wv;
  }
#pragma unroll
  for (int i = 0; i < 8; ++i)
    v_out[(size_t)(R0 + i) * F_ + tid] = fmaxf(acc[i], 0.f);
}

extern "C" void kernel_launch(void* const* d_in, const int* in_sizes, int n_in,
                              void* d_out, int out_size, void* d_ws, size_t ws_size,
                              hipStream_t stream) {
  const float* v_in = (const float*)d_in[0];
  const float* e_in = (const float*)d_in[1];
  const float* W_ev = (const float*)d_in[2];
  const float* b_ev = (const float*)d_in[3];
  const float* W_e  = (const float*)d_in[4];
  const float* b_e  = (const float*)d_in[5];
  const float* W_v  = (const float*)d_in[6];
  const float* b_v  = (const float*)d_in[7];

  float* out = (float*)d_out;
  float* v_out = out;                         // [32,128,128]
  float* e_out = out + (size_t)B_ * N_ * F_;  // [32,128,128,128]

  char* ws = (char*)d_ws;
  float* e_v = (float*)ws;                                   // 2 MB
  uint32_t* wpack = (uint32_t*)(ws + (size_t)2097152);       // 64 KB slot
  float* pve_part = (float*)(ws + (size_t)2097152 + 65536);  // 8 MB

  ev_kernel<<<(B_ * N_) / 8, 128, 0, stream>>>(v_in, W_ev, b_ev, e_v);
  pack_kernel<<<8, 256, 0, stream>>>(W_e, wpack);
  main_kernel<<<B_ * 8 * SPLIT_, 512, 0, stream>>>(e_in, e_v, b_e,
                                                   (const bf16x8*)wpack,
                                                   e_out, pve_part);
  v_kernel<<<(B_ * N_) / 8, 128, 0, stream>>>(v_in, pve_part, W_v, b_v, v_out);
}